// Round 2
// baseline (468.047 us; speedup 1.0000x reference)
//
#include <hip/hip_runtime.h>

#define NHEAD 16
#define WIN 256

typedef unsigned short u16;
typedef unsigned int u32;
typedef short bf16x8 __attribute__((ext_vector_type(8)));
typedef float floatx4 __attribute__((ext_vector_type(4)));
typedef u16 u16x4 __attribute__((ext_vector_type(4)));

__device__ __forceinline__ u16 f2bf(float f) {
    u32 u = __builtin_bit_cast(u32, f);
    u32 r = (u + 0x7fffu + ((u >> 16) & 1u)) >> 16;
    return (u16)r;
}
__device__ __forceinline__ float bf2f(u16 b) {
    u32 u = ((u32)b) << 16;
    return __builtin_bit_cast(float, u);
}

__device__ __forceinline__ void gload_lds16(const void* g, void* l) {
    __builtin_amdgcn_global_load_lds((const __attribute__((address_space(1))) u32*)g,
                                     (__attribute__((address_space(3))) u32*)l, 16, 0, 0);
}

// ---------------- f32 -> bf16 convert (vectorized) ----------------
__global__ void k_cvt(const float* __restrict__ in, u16* __restrict__ out, int n4) {
    int i = blockIdx.x * 256 + threadIdx.x;
    if (i >= n4) return;
    const floatx4 v = ((const floatx4*)in)[i];
    u16x4 o;
    o[0] = f2bf(v[0]); o[1] = f2bf(v[1]); o[2] = f2bf(v[2]); o[3] = f2bf(v[3]);
    ((u16x4*)out)[i] = o;
}

// ---------------- W [k][n] f32 -> Wt [n][k] bf16 ----------------
__global__ void k_transpose_w(const float* __restrict__ W, u16* __restrict__ Wt) {
    __shared__ float tile[32][33];
    const int tx = threadIdx.x & 31, ty = threadIdx.x >> 5; // ty in 0..7
    const int nb = blockIdx.x << 5, kb = blockIdx.y << 5;
#pragma unroll
    for (int i = 0; i < 4; ++i)
        tile[ty + 8 * i][tx] = W[(size_t)(kb + ty + 8 * i) * 1024 + nb + tx];
    __syncthreads();
#pragma unroll
    for (int i = 0; i < 4; ++i)
        Wt[(size_t)(nb + ty + 8 * i) * 1024 + kb + tx] = f2bf(tile[tx][ty + 8 * i]);
}

__global__ void k_concat_bias(const float* __restrict__ b0, const float* __restrict__ b1,
                              const float* __restrict__ b2, float* __restrict__ dst, int n) {
    int i = blockIdx.x * 256 + threadIdx.x;
    if (i >= n) return;
    dst[i] = (i < 1024) ? b0[i] : (i < 2048 ? b1[i - 1024] : b2[i - 2048]);
}

// ---------------- bf16 GEMM: C[M][N] = A[M][K] * Bt[N][K]^T + bias ----------------
// m97 structure: 128x128 tile, BK=64, 4 waves, global_load_lds w/ pre-swizzled source.
template <int OUT_BF16>
__launch_bounds__(256, 2)
__global__ void gemm_bt(const u16* __restrict__ A, const u16* __restrict__ Bt,
                        void* __restrict__ Cout, const float* __restrict__ bias,
                        int M, int N, int K) {
    __shared__ u16 smA[128 * 64];
    __shared__ u16 smB[128 * 64];
    const int t = threadIdx.x;
    const int l = t & 63, w = t >> 6;
    const int n0 = blockIdx.x << 7, m0 = blockIdx.y << 7;
    const int wm = w & 1, wn = w >> 1;
    floatx4 acc[4][4];
#pragma unroll
    for (int a = 0; a < 4; ++a)
#pragma unroll
        for (int bq = 0; bq < 4; ++bq) { floatx4 z = {0.f, 0.f, 0.f, 0.f}; acc[a][bq] = z; }

    const int nkt = K >> 6;
    for (int kt = 0; kt < nkt; ++kt) {
        const int k0 = kt << 6;
#pragma unroll
        for (int i = 0; i < 4; ++i) {
            int o = (w << 12) + (i << 10) + (l << 4);
            int row = o >> 7, colb = o & 127;
            int sc = colb ^ ((row & 7) << 4);
            gload_lds16((const char*)A + ((size_t)(m0 + row) * K + k0) * 2 + sc,
                        (char*)smA + (w << 12) + (i << 10));
            gload_lds16((const char*)Bt + ((size_t)(n0 + row) * K + k0) * 2 + sc,
                        (char*)smB + (w << 12) + (i << 10));
        }
        __syncthreads();
#pragma unroll
        for (int ks = 0; ks < 2; ++ks) {
            const int kb = ((ks << 5) + ((l >> 4) << 3)) << 1;
            bf16x8 am[4], bn[4];
#pragma unroll
            for (int mt = 0; mt < 4; ++mt) {
                int row = (wm << 6) + (mt << 4) + (l & 15);
                am[mt] = *(const bf16x8*)((const char*)smA + row * 128 + (kb ^ ((row & 7) << 4)));
            }
#pragma unroll
            for (int nt = 0; nt < 4; ++nt) {
                int row = (wn << 6) + (nt << 4) + (l & 15);
                bn[nt] = *(const bf16x8*)((const char*)smB + row * 128 + (kb ^ ((row & 7) << 4)));
            }
#pragma unroll
            for (int mt = 0; mt < 4; ++mt)
#pragma unroll
                for (int nt = 0; nt < 4; ++nt)
                    acc[mt][nt] = __builtin_amdgcn_mfma_f32_16x16x32_bf16(am[mt], bn[nt], acc[mt][nt], 0, 0, 0);
        }
        __syncthreads();
    }
    // epilogue
#pragma unroll
    for (int nt = 0; nt < 4; ++nt) {
        const int n = n0 + (wn << 6) + (nt << 4) + (l & 15);
        const float bv = bias[n];
#pragma unroll
        for (int mt = 0; mt < 4; ++mt) {
#pragma unroll
            for (int r = 0; r < 4; ++r) {
                int m = m0 + (wm << 6) + (mt << 4) + ((l >> 4) << 2) + r;
                float v = acc[mt][nt][r] + bv;
                if (OUT_BF16) ((u16*)Cout)[(size_t)m * N + n] = f2bf(v);
                else          ((float*)Cout)[(size_t)m * N + n] = v;
            }
        }
    }
}

// ---------------- fused banded attention ----------------
// grid (16 qtiles, 16 heads, 4 batch), 256 threads (4 waves), 64 queries/block.
// qkv: [4096][3072] bf16 (q|k|v), pqk: [4096][2048] bf16 (pq|pk)
// wei: [B,H,T,T] f32 out, att: [4096][1024] bf16 out
__launch_bounds__(256, 2)
__global__ void k_attn(const u16* __restrict__ qkv, const u16* __restrict__ pqk,
                       float* __restrict__ wei, u16* __restrict__ att) {
    __shared__ __align__(16) char sm[50176];
    u16* smQ  = (u16*)(sm);            // [64][64] swizzled (phase A)
    u16* smPQ = (u16*)(sm + 8192);     //   "
    u16* smK  = (u16*)(sm + 16384);    //   "    (per chunk)
    u16* smKm = (u16*)(sm + 24576);    //   "    (per chunk)
    u16* smP  = (u16*)(sm);            // [64 q][328 key] bf16 (phase B/C, overlaps A bufs; rows 0..63 end at 41984)
    u16* smVt = (u16*)(sm + 41984);    // [64 d][64 key] swizzled (phase C)

    const int t = threadIdx.x, l = t & 63, w = t >> 6;
    const int qt = blockIdx.x, h = blockIdx.y, b = blockIdx.z;
    const int q0 = qt << 6;
    const int jlo = (q0 - WIN) > 0 ? (q0 - WIN) : 0;
    const int nch = (qt + 1) < 5 ? (qt + 1) : 5;
    const int col_l = l & 15;
    const int rq_hi = (l >> 4) << 2;

    // ---- stage Q, PQ (pre-swizzled source -> linear LDS dest) ----
#pragma unroll
    for (int i = 0; i < 2; ++i) {
        int o = (w << 11) + (i << 10) + (l << 4);
        int row = o >> 7, colb = o & 127;
        int sc = colb ^ ((row & 7) << 4);
        gload_lds16((const char*)qkv + ((size_t)(b * 1024 + q0 + row) * 3072 + h * 64) * 2 + sc,
                    (char*)smQ + (w << 11) + (i << 10));
        gload_lds16((const char*)pqk + ((size_t)(b * 1024 + q0 + row) * 2048 + h * 64) * 2 + sc,
                    (char*)smPQ + (w << 11) + (i << 10));
    }

    floatx4 acc[20];
#pragma unroll
    for (int i = 0; i < 20; ++i) { floatx4 z = {0.f, 0.f, 0.f, 0.f}; acc[i] = z; }

    // ---- phase A: score MFMAs, chunk loop (compile-time unrolled for static acc idx) ----
#pragma unroll
    for (int c = 0; c < 5; ++c) {
        if (c < nch) {
            const int jb = jlo + (c << 6);
#pragma unroll
            for (int i = 0; i < 2; ++i) {
                int o = (w << 11) + (i << 10) + (l << 4);
                int row = o >> 7, colb = o & 127;
                int sc = colb ^ ((row & 7) << 4);
                gload_lds16((const char*)qkv + ((size_t)(b * 1024 + jb + row) * 3072 + 1024 + h * 64) * 2 + sc,
                            (char*)smK + (w << 11) + (i << 10));
            }
            { // Kmod = k/8 + pk (reg-staged, swizzled LDS writes)
                const int row = t >> 2, d0 = (t & 3) << 4;
                const u16* kp = qkv + (size_t)(b * 1024 + jb + row) * 3072 + 1024 + h * 64 + d0;
                const u16* pp = pqk + (size_t)(b * 1024 + jb + row) * 2048 + 1024 + h * 64 + d0;
                bf16x8 k0v = *(const bf16x8*)kp, k1v = *(const bf16x8*)(kp + 8);
                bf16x8 p0v = *(const bf16x8*)pp, p1v = *(const bf16x8*)(pp + 8);
                bf16x8 o0, o1;
#pragma unroll
                for (int j = 0; j < 8; ++j) {
                    o0[j] = (short)f2bf(0.125f * bf2f((u16)k0v[j]) + bf2f((u16)p0v[j]));
                    o1[j] = (short)f2bf(0.125f * bf2f((u16)k1v[j]) + bf2f((u16)p1v[j]));
                }
                const int sw = (row & 7) << 4;
                *(bf16x8*)((char*)smKm + row * 128 + ((d0 * 2) ^ sw)) = o0;
                *(bf16x8*)((char*)smKm + row * 128 + ((d0 * 2 + 16) ^ sw)) = o1;
            }
            __syncthreads();
#pragma unroll
            for (int ks = 0; ks < 2; ++ks) {
                const int kb = ((ks << 5) + ((l >> 4) << 3)) << 1;
                const int rq = (w << 4) + (l & 15);
                bf16x8 aQ  = *(const bf16x8*)((const char*)smQ  + rq * 128 + (kb ^ ((rq & 7) << 4)));
                bf16x8 aPQ = *(const bf16x8*)((const char*)smPQ + rq * 128 + (kb ^ ((rq & 7) << 4)));
#pragma unroll
                for (int s = 0; s < 4; ++s) {
                    const int rk = (s << 4) + (l & 15);
                    bf16x8 bKm = *(const bf16x8*)((const char*)smKm + rk * 128 + (kb ^ ((rk & 7) << 4)));
                    bf16x8 bK  = *(const bf16x8*)((const char*)smK  + rk * 128 + (kb ^ ((rk & 7) << 4)));
                    acc[c * 4 + s] = __builtin_amdgcn_mfma_f32_16x16x32_bf16(aQ,  bKm, acc[c * 4 + s], 0, 0, 0);
                    acc[c * 4 + s] = __builtin_amdgcn_mfma_f32_16x16x32_bf16(aPQ, bK,  acc[c * 4 + s], 0, 0, 0);
                }
            }
            __syncthreads();
        }
    }

    // ---- phase B: softmax in MFMA-accumulator layout; write wei band + P(bf16) ----
    const float inv_s192 = 0.07216878364870323f; // 1/sqrt(3*64)
    const float slope = exp2f(-0.5f * (float)(h + 1));
    const int ntiles = nch << 2;
#pragma unroll
    for (int r = 0; r < 4; ++r) {
        const int iq = q0 + (w << 4) + rq_hi + r;
        float mx = -1e30f;
#pragma unroll
        for (int ti = 0; ti < 20; ++ti) {
            int j = jlo + (ti << 4) + col_l;
            float s = acc[ti][r] * inv_s192 - slope * (float)(iq - j);
            bool ok = (ti < ntiles) && (j <= iq) && (j >= iq - WIN);
            s = ok ? s : -1e30f;
            acc[ti][r] = s;
            mx = fmaxf(mx, s);
        }
        mx = fmaxf(mx, __shfl_xor(mx, 1));
        mx = fmaxf(mx, __shfl_xor(mx, 2));
        mx = fmaxf(mx, __shfl_xor(mx, 4));
        mx = fmaxf(mx, __shfl_xor(mx, 8));
        float sum = 0.f;
#pragma unroll
        for (int ti = 0; ti < 20; ++ti) {
            float p = __expf(acc[ti][r] - mx);
            acc[ti][r] = p;
            sum += p;
        }
        sum += __shfl_xor(sum, 1); sum += __shfl_xor(sum, 2);
        sum += __shfl_xor(sum, 4); sum += __shfl_xor(sum, 8);
        const float inv = 1.0f / sum;
        float* wrow = wei + ((((size_t)(b * NHEAD + h)) << 10) + iq) * 1024;
#pragma unroll
        for (int ti = 0; ti < 20; ++ti) {
            if (ti < ntiles) {
                float p = acc[ti][r] * inv;
                int j = jlo + (ti << 4) + col_l;
                wrow[j] = p;
                smP[((w << 4) + rq_hi + r) * 328 + (ti << 4) + col_l] = f2bf(p);
            }
        }
    }
    // zero-fill wei outside [jlo, q0+64)
    {
        const int zlen1 = jlo;
        const int zstart2 = q0 + 64;
        const int zlen2 = 1024 - zstart2;
        const int nz4 = (zlen1 + zlen2) >> 2;
        float* wbase = wei + (((size_t)(b * NHEAD + h)) << 20);
        for (int idx = t; idx < nz4 * 64; idx += 256) {
            int rrow = idx / nz4;
            int off4 = (idx - rrow * nz4) << 2;
            int col = (off4 < zlen1) ? off4 : (zstart2 + (off4 - zlen1));
            floatx4 z = {0.f, 0.f, 0.f, 0.f};
            *(floatx4*)(wbase + (((size_t)(q0 + rrow)) << 10) + col) = z;
        }
    }

    // ---- phase C: O = P * V  (V staged TRANSPOSED into LDS: smVt[d][key], swizzled) ----
    floatx4 acco[4];
#pragma unroll
    for (int s = 0; s < 4; ++s) { floatx4 z = {0.f, 0.f, 0.f, 0.f}; acco[s] = z; }
    const int vkey = t & 63, vdb = (t >> 6) << 4;
    for (int c = 0; c < nch; ++c) {
        const int jb = jlo + (c << 6);
        { // reg-stage V chunk [64 key][64 d] -> smVt[d][key] (scatter, conflict-free writes)
            const u16* vp = qkv + (size_t)(b * 1024 + jb + vkey) * 3072 + 2048 + h * 64 + vdb;
            bf16x8 v0 = *(const bf16x8*)vp;
            bf16x8 v1 = *(const bf16x8*)(vp + 8);
            const int kx = vkey << 1;
#pragma unroll
            for (int j = 0; j < 8; ++j) {
                const int d0 = vdb + j, d1 = vdb + 8 + j;
                *(u16*)((char*)smVt + d0 * 128 + (kx ^ ((d0 & 7) << 4))) = (u16)v0[j];
                *(u16*)((char*)smVt + d1 * 128 + (kx ^ ((d1 & 7) << 4))) = (u16)v1[j];
            }
        }
        __syncthreads();
#pragma unroll
        for (int ks = 0; ks < 2; ++ks) {
            const int rp = (w << 4) + (l & 15);
            const int keyb = ((c << 6) + (ks << 5) + ((l >> 4) << 3)) << 1;
            bf16x8 aP = *(const bf16x8*)((const char*)smP + rp * 656 + keyb);
            const int klb = ((ks << 5) + ((l >> 4) << 3)) << 1;
#pragma unroll
            for (int s = 0; s < 4; ++s) {
                const int d = (s << 4) + col_l;
                bf16x8 bV = *(const bf16x8*)((const char*)smVt + d * 128 + (klb ^ ((d & 7) << 4)));
                acco[s] = __builtin_amdgcn_mfma_f32_16x16x32_bf16(aP, bV, acco[s], 0, 0, 0);
            }
        }
        __syncthreads();
    }
#pragma unroll
    for (int s = 0; s < 4; ++s) {
#pragma unroll
        for (int r = 0; r < 4; ++r) {
            const int iq = q0 + (w << 4) + rq_hi + r;
            const int d = (s << 4) + col_l;
            att[(((size_t)(b * 1024 + iq)) << 10) + h * 64 + d] = f2bf(acco[s][r]);
        }
    }
}

extern "C" void kernel_launch(void* const* d_in, const int* in_sizes, int n_in,
                              void* d_out, int out_size, void* d_ws, size_t ws_size,
                              hipStream_t stream) {
    const float* x   = (const float*)d_in[0];
    const float* pos = (const float*)d_in[1];
    const float* Wq  = (const float*)d_in[2];
    const float* bq  = (const float*)d_in[3];
    const float* Wk  = (const float*)d_in[4];
    const float* bk  = (const float*)d_in[5];
    const float* Wv  = (const float*)d_in[6];
    const float* bv  = (const float*)d_in[7];
    const float* Wpq = (const float*)d_in[8];
    const float* bpq = (const float*)d_in[9];
    const float* Wpk = (const float*)d_in[10];
    const float* bpk = (const float*)d_in[11];
    const float* Wo  = (const float*)d_in[12];
    const float* bo  = (const float*)d_in[13];

    char* ws = (char*)d_ws;
    u16*   xb    = (u16*)(ws);                 // 8 MB  [4096][1024] bf16 (also reused as att)
    u16*   pb    = (u16*)(ws + 8388608);       // 8 MB
    u16*   wtqkv = (u16*)(ws + 16777216);      // 6 MB  [3072][1024]
    u16*   wtp   = (u16*)(ws + 23068672);      // 4 MB  [2048][1024]
    u16*   wto   = (u16*)(ws + 27262976);      // 2 MB  [1024][1024]
    float* bqkv  = (float*)(ws + 29360128);    // 12 KB
    float* bp    = (float*)(ws + 29372416);    // 8 KB
    u16*   qkv   = (u16*)(ws + 29380608);      // 24 MB [4096][3072]
    u16*   pqk   = (u16*)(ws + 54546432);      // 16 MB [4096][2048]
    u16*   att   = xb;                         // alias: xb dead after GEMM1

    float* out0 = (float*)d_out;
    float* wei  = (float*)d_out + 4194304;

    k_cvt<<<4096, 256, 0, stream>>>(x,   xb, 1048576);
    k_cvt<<<4096, 256, 0, stream>>>(pos, pb, 1048576);
    dim3 tg(32, 32);
    k_transpose_w<<<tg, 256, 0, stream>>>(Wq,  wtqkv);
    k_transpose_w<<<tg, 256, 0, stream>>>(Wk,  wtqkv + 1048576);
    k_transpose_w<<<tg, 256, 0, stream>>>(Wv,  wtqkv + 2097152);
    k_transpose_w<<<tg, 256, 0, stream>>>(Wpq, wtp);
    k_transpose_w<<<tg, 256, 0, stream>>>(Wpk, wtp + 1048576);
    k_transpose_w<<<tg, 256, 0, stream>>>(Wo,  wto);
    k_concat_bias<<<12, 256, 0, stream>>>(bq,  bk,  bv,  bqkv, 3072);
    k_concat_bias<<<8,  256, 0, stream>>>(bpq, bpk, bpk, bp,   2048);

    gemm_bt<1><<<dim3(24, 32), 256, 0, stream>>>(xb, wtqkv, qkv, bqkv, 4096, 3072, 1024);
    gemm_bt<1><<<dim3(16, 32), 256, 0, stream>>>(pb, wtp,   pqk, bp,   4096, 2048, 1024);

    k_attn<<<dim3(16, 16, 4), 256, 0, stream>>>(qkv, pqk, wei, att);

    gemm_bt<0><<<dim3(8, 32), 256, 0, stream>>>(att, wto, out0, bo, 4096, 1024, 1024);
}

// Round 3
// 454.178 us; speedup vs baseline: 1.0305x; 1.0305x over previous
//
#include <hip/hip_runtime.h>

#define NHEAD 16
#define WIN 256

typedef unsigned short u16;
typedef unsigned int u32;
typedef short bf16x8 __attribute__((ext_vector_type(8)));
typedef float floatx4 __attribute__((ext_vector_type(4)));
typedef u16 u16x4 __attribute__((ext_vector_type(4)));

__device__ __forceinline__ u16 f2bf(float f) {
    u32 u = __builtin_bit_cast(u32, f);
    u32 r = (u + 0x7fffu + ((u >> 16) & 1u)) >> 16;
    return (u16)r;
}
__device__ __forceinline__ float bf2f(u16 b) {
    u32 u = ((u32)b) << 16;
    return __builtin_bit_cast(float, u);
}

__device__ __forceinline__ void gload_lds16(const void* g, void* l) {
    __builtin_amdgcn_global_load_lds((const __attribute__((address_space(1))) u32*)g,
                                     (__attribute__((address_space(3))) u32*)l, 16, 0, 0);
}

// ---------------- inputs f32 -> bf16 (x and pos in one launch) ----------------
__global__ void k_prep_in(const float* __restrict__ x, const float* __restrict__ pos,
                          u16* __restrict__ xb, u16* __restrict__ pb) {
    int i = blockIdx.x * 256 + threadIdx.x;          // 0 .. 2097151 (float4 units)
    const float* src = x; u16* dst = xb;
    int j = i;
    if (i >= 1048576) { src = pos; dst = pb; j = i - 1048576; }
    const floatx4 v = ((const floatx4*)src)[j];
    u16x4 o;
    o[0] = f2bf(v[0]); o[1] = f2bf(v[1]); o[2] = f2bf(v[2]); o[3] = f2bf(v[3]);
    ((u16x4*)dst)[j] = o;
}

// ---------------- all 6 weight transposes in one launch (z selects) ----------------
__global__ void k_prep_w(const float* __restrict__ Wq, const float* __restrict__ Wk,
                         const float* __restrict__ Wv, const float* __restrict__ Wpq,
                         const float* __restrict__ Wpk, const float* __restrict__ Wo,
                         u16* __restrict__ wtqkv, u16* __restrict__ wtp, u16* __restrict__ wto) {
    __shared__ float tile[32][33];
    const int z = blockIdx.z;
    const float* W; u16* Wt;
    switch (z) {
        case 0: W = Wq;  Wt = wtqkv;           break;
        case 1: W = Wk;  Wt = wtqkv + 1048576; break;
        case 2: W = Wv;  Wt = wtqkv + 2097152; break;
        case 3: W = Wpq; Wt = wtp;             break;
        case 4: W = Wpk; Wt = wtp + 1048576;   break;
        default: W = Wo; Wt = wto;             break;
    }
    const int tx = threadIdx.x & 31, ty = threadIdx.x >> 5;
    const int nb = blockIdx.x << 5, kb = blockIdx.y << 5;
#pragma unroll
    for (int i = 0; i < 4; ++i)
        tile[ty + 8 * i][tx] = W[(size_t)(kb + ty + 8 * i) * 1024 + nb + tx];
    __syncthreads();
#pragma unroll
    for (int i = 0; i < 4; ++i)
        Wt[(size_t)(nb + ty + 8 * i) * 1024 + kb + tx] = f2bf(tile[tx][ty + 8 * i]);
}

// ---------------- both bias concats in one launch ----------------
__global__ void k_concat_bias(const float* __restrict__ bq, const float* __restrict__ bk,
                              const float* __restrict__ bv, const float* __restrict__ bpq,
                              const float* __restrict__ bpk,
                              float* __restrict__ bqkv, float* __restrict__ bp) {
    int i = blockIdx.x * 256 + threadIdx.x;          // 0..5119
    if (i >= 5120) return;
    float v; float* d;
    if (i < 1024)      { v = bq[i];         d = bqkv + i; }
    else if (i < 2048) { v = bk[i - 1024];  d = bqkv + i; }
    else if (i < 3072) { v = bv[i - 2048];  d = bqkv + i; }
    else if (i < 4096) { v = bpq[i - 3072]; d = bp + (i - 3072); }
    else               { v = bpk[i - 4096]; d = bp + (i - 3072); }
    *d = v;
}

// ---------------- fused projection GEMM: [qkv | pqk] in one launch ----------------
// m97 structure: 128x128 tile, BK=64, 4 waves, global_load_lds w/ pre-swizzled source.
__launch_bounds__(256, 2)
__global__ void gemm_proj(const u16* __restrict__ A0, const u16* __restrict__ Bt0,
                          u16* __restrict__ C0, const float* __restrict__ bias0, int nblk0, int N0,
                          const u16* __restrict__ A1, const u16* __restrict__ Bt1,
                          u16* __restrict__ C1, const float* __restrict__ bias1, int N1,
                          int M, int K) {
    __shared__ u16 smA[128 * 64];
    __shared__ u16 smB[128 * 64];
    const int t = threadIdx.x;
    const int l = t & 63, w = t >> 6;
    const int bx = blockIdx.x;
    const u16* A; const u16* Bt; u16* C; const float* bias; int N, n0;
    if (bx < nblk0) { A = A0; Bt = Bt0; C = C0; bias = bias0; N = N0; n0 = bx << 7; }
    else            { A = A1; Bt = Bt1; C = C1; bias = bias1; N = N1; n0 = (bx - nblk0) << 7; }
    const int m0 = blockIdx.y << 7;
    const int wm = w & 1, wn = w >> 1;
    floatx4 acc[4][4];
#pragma unroll
    for (int a = 0; a < 4; ++a)
#pragma unroll
        for (int bq = 0; bq < 4; ++bq) { floatx4 z = {0.f, 0.f, 0.f, 0.f}; acc[a][bq] = z; }

    const int nkt = K >> 6;
    for (int kt = 0; kt < nkt; ++kt) {
        const int k0 = kt << 6;
#pragma unroll
        for (int i = 0; i < 4; ++i) {
            int o = (w << 12) + (i << 10) + (l << 4);
            int row = o >> 7, colb = o & 127;
            int sc = colb ^ ((row & 7) << 4);
            gload_lds16((const char*)A + ((size_t)(m0 + row) * K + k0) * 2 + sc,
                        (char*)smA + (w << 12) + (i << 10));
            gload_lds16((const char*)Bt + ((size_t)(n0 + row) * K + k0) * 2 + sc,
                        (char*)smB + (w << 12) + (i << 10));
        }
        __syncthreads();
#pragma unroll
        for (int ks = 0; ks < 2; ++ks) {
            const int kb = ((ks << 5) + ((l >> 4) << 3)) << 1;
            bf16x8 am[4], bn[4];
#pragma unroll
            for (int mt = 0; mt < 4; ++mt) {
                int row = (wm << 6) + (mt << 4) + (l & 15);
                am[mt] = *(const bf16x8*)((const char*)smA + row * 128 + (kb ^ ((row & 7) << 4)));
            }
#pragma unroll
            for (int nt = 0; nt < 4; ++nt) {
                int row = (wn << 6) + (nt << 4) + (l & 15);
                bn[nt] = *(const bf16x8*)((const char*)smB + row * 128 + (kb ^ ((row & 7) << 4)));
            }
#pragma unroll
            for (int mt = 0; mt < 4; ++mt)
#pragma unroll
                for (int nt = 0; nt < 4; ++nt)
                    acc[mt][nt] = __builtin_amdgcn_mfma_f32_16x16x32_bf16(am[mt], bn[nt], acc[mt][nt], 0, 0, 0);
        }
        __syncthreads();
    }
#pragma unroll
    for (int nt = 0; nt < 4; ++nt) {
        const int n = n0 + (wn << 6) + (nt << 4) + (l & 15);
        const float bv = bias[n];
#pragma unroll
        for (int mt = 0; mt < 4; ++mt) {
#pragma unroll
            for (int r = 0; r < 4; ++r) {
                int m = m0 + (wm << 6) + (mt << 4) + ((l >> 4) << 2) + r;
                C[(size_t)m * N + n] = f2bf(acc[mt][nt][r] + bv);
            }
        }
    }
}

// ---------------- final GEMM: C f32 = A bf16 * Bt^T + bias ----------------
__launch_bounds__(256, 2)
__global__ void gemm_bt_f32(const u16* __restrict__ A, const u16* __restrict__ Bt,
                            float* __restrict__ Cout, const float* __restrict__ bias,
                            int M, int N, int K) {
    __shared__ u16 smA[128 * 64];
    __shared__ u16 smB[128 * 64];
    const int t = threadIdx.x;
    const int l = t & 63, w = t >> 6;
    const int n0 = blockIdx.x << 7, m0 = blockIdx.y << 7;
    const int wm = w & 1, wn = w >> 1;
    floatx4 acc[4][4];
#pragma unroll
    for (int a = 0; a < 4; ++a)
#pragma unroll
        for (int bq = 0; bq < 4; ++bq) { floatx4 z = {0.f, 0.f, 0.f, 0.f}; acc[a][bq] = z; }

    const int nkt = K >> 6;
    for (int kt = 0; kt < nkt; ++kt) {
        const int k0 = kt << 6;
#pragma unroll
        for (int i = 0; i < 4; ++i) {
            int o = (w << 12) + (i << 10) + (l << 4);
            int row = o >> 7, colb = o & 127;
            int sc = colb ^ ((row & 7) << 4);
            gload_lds16((const char*)A + ((size_t)(m0 + row) * K + k0) * 2 + sc,
                        (char*)smA + (w << 12) + (i << 10));
            gload_lds16((const char*)Bt + ((size_t)(n0 + row) * K + k0) * 2 + sc,
                        (char*)smB + (w << 12) + (i << 10));
        }
        __syncthreads();
#pragma unroll
        for (int ks = 0; ks < 2; ++ks) {
            const int kb = ((ks << 5) + ((l >> 4) << 3)) << 1;
            bf16x8 am[4], bn[4];
#pragma unroll
            for (int mt = 0; mt < 4; ++mt) {
                int row = (wm << 6) + (mt << 4) + (l & 15);
                am[mt] = *(const bf16x8*)((const char*)smA + row * 128 + (kb ^ ((row & 7) << 4)));
            }
#pragma unroll
            for (int nt = 0; nt < 4; ++nt) {
                int row = (wn << 6) + (nt << 4) + (l & 15);
                bn[nt] = *(const bf16x8*)((const char*)smB + row * 128 + (kb ^ ((row & 7) << 4)));
            }
#pragma unroll
            for (int mt = 0; mt < 4; ++mt)
#pragma unroll
                for (int nt = 0; nt < 4; ++nt)
                    acc[mt][nt] = __builtin_amdgcn_mfma_f32_16x16x32_bf16(am[mt], bn[nt], acc[mt][nt], 0, 0, 0);
        }
        __syncthreads();
    }
#pragma unroll
    for (int nt = 0; nt < 4; ++nt) {
        const int n = n0 + (wn << 6) + (nt << 4) + (l & 15);
        const float bv = bias[n];
#pragma unroll
        for (int mt = 0; mt < 4; ++mt) {
#pragma unroll
            for (int r = 0; r < 4; ++r) {
                int m = m0 + (wm << 6) + (mt << 4) + ((l >> 4) << 2) + r;
                Cout[(size_t)m * N + n] = acc[mt][nt][r] + bv;
            }
        }
    }
}

// ---------------- fused banded attention ----------------
// grid (16 qtiles, 16 heads, 4 batch), 256 threads (4 waves), 64 queries/block.
__launch_bounds__(256, 2)
__global__ void k_attn(const u16* __restrict__ qkv, const u16* __restrict__ pqk,
                       float* __restrict__ wei, u16* __restrict__ att) {
    __shared__ __align__(16) char sm[50176];
    u16* smQ  = (u16*)(sm);            // [64][64] swizzled (phase A)
    u16* smPQ = (u16*)(sm + 8192);
    u16* smK  = (u16*)(sm + 16384);
    u16* smKm = (u16*)(sm + 24576);
    u16* smP  = (u16*)(sm);            // [64 q][328 key] bf16 (phase B/C)
    u16* smVt = (u16*)(sm + 41984);    // [64 d][64 key] swizzled (phase C)

    const int t = threadIdx.x, l = t & 63, w = t >> 6;
    const int qt = blockIdx.x, h = blockIdx.y, b = blockIdx.z;
    const int q0 = qt << 6;
    const int jlo = (q0 - WIN) > 0 ? (q0 - WIN) : 0;
    const int nch = (qt + 1) < 5 ? (qt + 1) : 5;
    const int col_l = l & 15;
    const int rq_hi = (l >> 4) << 2;

    // ---- stage Q, PQ (pre-swizzled source -> linear LDS dest) ----
#pragma unroll
    for (int i = 0; i < 2; ++i) {
        int o = (w << 11) + (i << 10) + (l << 4);
        int row = o >> 7, colb = o & 127;
        int sc = colb ^ ((row & 7) << 4);
        gload_lds16((const char*)qkv + ((size_t)(b * 1024 + q0 + row) * 3072 + h * 64) * 2 + sc,
                    (char*)smQ + (w << 11) + (i << 10));
        gload_lds16((const char*)pqk + ((size_t)(b * 1024 + q0 + row) * 2048 + h * 64) * 2 + sc,
                    (char*)smPQ + (w << 11) + (i << 10));
    }

    // ---- early zero-fill of wei outside the band (overlaps load latency) ----
    {
        const int zlen1 = jlo;                 // [0, jlo)
        const int zstart2 = q0 + 64;           // [q0+64, 1024)
        const int nz4 = (zlen1 + (1024 - zstart2)) >> 2;
        float* wbase = wei + (((size_t)(b * NHEAD + h)) << 20);
        floatx4 z4 = {0.f, 0.f, 0.f, 0.f};
        for (int rr = w; rr < 64; rr += 4) {
            float* rowp = wbase + (((size_t)(q0 + rr)) << 10);
            for (int cc = l; cc < nz4; cc += 64) {
                int off4 = cc << 2;
                int col = (off4 < zlen1) ? off4 : (zstart2 + (off4 - zlen1));
                *(floatx4*)(rowp + col) = z4;
            }
        }
    }

    floatx4 acc[20];
#pragma unroll
    for (int i = 0; i < 20; ++i) { floatx4 z = {0.f, 0.f, 0.f, 0.f}; acc[i] = z; }

    // ---- phase A: score MFMAs with K/PK register prefetch ----
    const int prow = t >> 2, pd0 = (t & 3) << 4;
    bf16x8 rk0, rk1, rp0, rp1;
    {
        const u16* kp = qkv + (size_t)(b * 1024 + jlo + prow) * 3072 + 1024 + h * 64 + pd0;
        const u16* pp = pqk + (size_t)(b * 1024 + jlo + prow) * 2048 + 1024 + h * 64 + pd0;
        rk0 = *(const bf16x8*)kp; rk1 = *(const bf16x8*)(kp + 8);
        rp0 = *(const bf16x8*)pp; rp1 = *(const bf16x8*)(pp + 8);
    }
#pragma unroll
    for (int c = 0; c < 5; ++c) {
        if (c < nch) {
            const int jb = jlo + (c << 6);
            { // Kmod = k/8 + pk from prefetched regs -> swizzled LDS
                bf16x8 o0, o1;
#pragma unroll
                for (int j = 0; j < 8; ++j) {
                    o0[j] = (short)f2bf(0.125f * bf2f((u16)rk0[j]) + bf2f((u16)rp0[j]));
                    o1[j] = (short)f2bf(0.125f * bf2f((u16)rk1[j]) + bf2f((u16)rp1[j]));
                }
                const int sw = (prow & 7) << 4;
                *(bf16x8*)((char*)smKm + prow * 128 + ((pd0 * 2) ^ sw)) = o0;
                *(bf16x8*)((char*)smKm + prow * 128 + ((pd0 * 2 + 16) ^ sw)) = o1;
            }
#pragma unroll
            for (int i = 0; i < 2; ++i) {
                int o = (w << 11) + (i << 10) + (l << 4);
                int row = o >> 7, colb = o & 127;
                int sc = colb ^ ((row & 7) << 4);
                gload_lds16((const char*)qkv + ((size_t)(b * 1024 + jb + row) * 3072 + 1024 + h * 64) * 2 + sc,
                            (char*)smK + (w << 11) + (i << 10));
            }
            __syncthreads();
            if (c + 1 < nch) { // prefetch next chunk's K/PK into regs (overlaps MFMA)
                const int jb2 = jlo + ((c + 1) << 6);
                const u16* kp = qkv + (size_t)(b * 1024 + jb2 + prow) * 3072 + 1024 + h * 64 + pd0;
                const u16* pp = pqk + (size_t)(b * 1024 + jb2 + prow) * 2048 + 1024 + h * 64 + pd0;
                rk0 = *(const bf16x8*)kp; rk1 = *(const bf16x8*)(kp + 8);
                rp0 = *(const bf16x8*)pp; rp1 = *(const bf16x8*)(pp + 8);
            }
            __builtin_amdgcn_s_setprio(1);
#pragma unroll
            for (int ks = 0; ks < 2; ++ks) {
                const int kb = ((ks << 5) + ((l >> 4) << 3)) << 1;
                const int rq = (w << 4) + (l & 15);
                bf16x8 aQ  = *(const bf16x8*)((const char*)smQ  + rq * 128 + (kb ^ ((rq & 7) << 4)));
                bf16x8 aPQ = *(const bf16x8*)((const char*)smPQ + rq * 128 + (kb ^ ((rq & 7) << 4)));
#pragma unroll
                for (int s = 0; s < 4; ++s) {
                    const int rk = (s << 4) + (l & 15);
                    bf16x8 bKm = *(const bf16x8*)((const char*)smKm + rk * 128 + (kb ^ ((rk & 7) << 4)));
                    bf16x8 bK  = *(const bf16x8*)((const char*)smK  + rk * 128 + (kb ^ ((rk & 7) << 4)));
                    acc[c * 4 + s] = __builtin_amdgcn_mfma_f32_16x16x32_bf16(aQ,  bKm, acc[c * 4 + s], 0, 0, 0);
                    acc[c * 4 + s] = __builtin_amdgcn_mfma_f32_16x16x32_bf16(aPQ, bK,  acc[c * 4 + s], 0, 0, 0);
                }
            }
            __builtin_amdgcn_s_setprio(0);
            __syncthreads();
        }
    }

    // ---- phase B: softmax in MFMA-accumulator layout; write wei band + P(bf16) ----
    const float inv_s192 = 0.07216878364870323f; // 1/sqrt(3*64)
    const float slope = exp2f(-0.5f * (float)(h + 1));
    const int ntiles = nch << 2;
#pragma unroll
    for (int r = 0; r < 4; ++r) {
        const int iq = q0 + (w << 4) + rq_hi + r;
        float mx = -1e30f;
#pragma unroll
        for (int ti = 0; ti < 20; ++ti) {
            int j = jlo + (ti << 4) + col_l;
            float s = acc[ti][r] * inv_s192 - slope * (float)(iq - j);
            bool ok = (ti < ntiles) && (j <= iq) && (j >= iq - WIN);
            s = ok ? s : -1e30f;
            acc[ti][r] = s;
            mx = fmaxf(mx, s);
        }
        mx = fmaxf(mx, __shfl_xor(mx, 1));
        mx = fmaxf(mx, __shfl_xor(mx, 2));
        mx = fmaxf(mx, __shfl_xor(mx, 4));
        mx = fmaxf(mx, __shfl_xor(mx, 8));
        float sum = 0.f;
#pragma unroll
        for (int ti = 0; ti < 20; ++ti) {
            float p = __expf(acc[ti][r] - mx);
            acc[ti][r] = p;
            sum += p;
        }
        sum += __shfl_xor(sum, 1); sum += __shfl_xor(sum, 2);
        sum += __shfl_xor(sum, 4); sum += __shfl_xor(sum, 8);
        const float inv = 1.0f / sum;
        float* wrow = wei + ((((size_t)(b * NHEAD + h)) << 10) + iq) * 1024;
#pragma unroll
        for (int ti = 0; ti < 20; ++ti) {
            if (ti < ntiles) {
                float p = acc[ti][r] * inv;
                int j = jlo + (ti << 4) + col_l;
                wrow[j] = p;
                smP[((w << 4) + rq_hi + r) * 328 + (ti << 4) + col_l] = f2bf(p);
            }
        }
    }

    // ---- phase C: O = P * V  (V staged transposed, reg-prefetched) ----
    floatx4 acco[4];
#pragma unroll
    for (int s = 0; s < 4; ++s) { floatx4 z = {0.f, 0.f, 0.f, 0.f}; acco[s] = z; }
    const int vkey = t & 63, vdb = (t >> 6) << 4;
    bf16x8 v0, v1;
    {
        const u16* vp = qkv + (size_t)(b * 1024 + jlo + vkey) * 3072 + 2048 + h * 64 + vdb;
        v0 = *(const bf16x8*)vp; v1 = *(const bf16x8*)(vp + 8);
    }
#pragma unroll
    for (int c = 0; c < 5; ++c) {
        if (c < nch) {
            { // scatter prefetched V chunk -> smVt[d][key] (swizzled)
                const int kx = vkey << 1;
#pragma unroll
                for (int j = 0; j < 8; ++j) {
                    const int d0 = vdb + j, d1 = vdb + 8 + j;
                    *(u16*)((char*)smVt + d0 * 128 + (kx ^ ((d0 & 7) << 4))) = (u16)v0[j];
                    *(u16*)((char*)smVt + d1 * 128 + (kx ^ ((d1 & 7) << 4))) = (u16)v1[j];
                }
            }
            __syncthreads();
            if (c + 1 < nch) {
                const u16* vp = qkv + (size_t)(b * 1024 + jlo + ((c + 1) << 6) + vkey) * 3072 + 2048 + h * 64 + vdb;
                v0 = *(const bf16x8*)vp; v1 = *(const bf16x8*)(vp + 8);
            }
            __builtin_amdgcn_s_setprio(1);
#pragma unroll
            for (int ks = 0; ks < 2; ++ks) {
                const int rp = (w << 4) + (l & 15);
                const int keyb = ((c << 6) + (ks << 5) + ((l >> 4) << 3)) << 1;
                bf16x8 aP = *(const bf16x8*)((const char*)smP + rp * 656 + keyb);
                const int klb = ((ks << 5) + ((l >> 4) << 3)) << 1;
#pragma unroll
                for (int s = 0; s < 4; ++s) {
                    const int d = (s << 4) + col_l;
                    bf16x8 bV = *(const bf16x8*)((const char*)smVt + d * 128 + (klb ^ ((d & 7) << 4)));
                    acco[s] = __builtin_amdgcn_mfma_f32_16x16x32_bf16(aP, bV, acco[s], 0, 0, 0);
                }
            }
            __builtin_amdgcn_s_setprio(0);
            __syncthreads();
        }
    }
#pragma unroll
    for (int s = 0; s < 4; ++s) {
#pragma unroll
        for (int r = 0; r < 4; ++r) {
            const int iq = q0 + (w << 4) + rq_hi + r;
            const int d = (s << 4) + col_l;
            att[(((size_t)(b * 1024 + iq)) << 10) + h * 64 + d] = f2bf(acco[s][r]);
        }
    }
}

extern "C" void kernel_launch(void* const* d_in, const int* in_sizes, int n_in,
                              void* d_out, int out_size, void* d_ws, size_t ws_size,
                              hipStream_t stream) {
    const float* x   = (const float*)d_in[0];
    const float* pos = (const float*)d_in[1];
    const float* Wq  = (const float*)d_in[2];
    const float* bq  = (const float*)d_in[3];
    const float* Wk  = (const float*)d_in[4];
    const float* bk  = (const float*)d_in[5];
    const float* Wv  = (const float*)d_in[6];
    const float* bv  = (const float*)d_in[7];
    const float* Wpq = (const float*)d_in[8];
    const float* bpq = (const float*)d_in[9];
    const float* Wpk = (const float*)d_in[10];
    const float* bpk = (const float*)d_in[11];
    const float* Wo  = (const float*)d_in[12];
    const float* bo  = (const float*)d_in[13];

    char* ws = (char*)d_ws;
    u16*   xb    = (u16*)(ws);                 // 8 MB  [4096][1024] bf16 (reused as att)
    u16*   pb    = (u16*)(ws + 8388608);       // 8 MB
    u16*   wtqkv = (u16*)(ws + 16777216);      // 6 MB  [3072][1024]
    u16*   wtp   = (u16*)(ws + 23068672);      // 4 MB  [2048][1024]
    u16*   wto   = (u16*)(ws + 27262976);      // 2 MB  [1024][1024]
    float* bqkv  = (float*)(ws + 29360128);    // 12 KB
    float* bp    = (float*)(ws + 29372416);    // 8 KB
    u16*   qkv   = (u16*)(ws + 29380608);      // 24 MB [4096][3072]
    u16*   pqk   = (u16*)(ws + 54546432);      // 16 MB [4096][2048]
    u16*   att   = xb;                         // alias: xb dead after projection

    float* out0 = (float*)d_out;
    float* wei  = (float*)d_out + 4194304;

    k_prep_in<<<8192, 256, 0, stream>>>(x, pos, xb, pb);
    k_prep_w<<<dim3(32, 32, 6), 256, 0, stream>>>(Wq, Wk, Wv, Wpq, Wpk, Wo, wtqkv, wtp, wto);
    k_concat_bias<<<20, 256, 0, stream>>>(bq, bk, bv, bpq, bpk, bqkv, bp);

    gemm_proj<<<dim3(40, 32), 256, 0, stream>>>(xb, wtqkv, qkv, bqkv, 24, 3072,
                                                pb, wtp, pqk, bp, 2048, 4096, 1024);

    k_attn<<<dim3(16, 16, 4), 256, 0, stream>>>(qkv, pqk, wei, att);

    gemm_bt_f32<<<dim3(8, 32), 256, 0, stream>>>(att, wto, out0, bo, 4096, 1024, 1024);
}

// Round 4
// 446.739 us; speedup vs baseline: 1.0477x; 1.0167x over previous
//
#include <hip/hip_runtime.h>

#define NHEAD 16
#define WIN 256

typedef unsigned short u16;
typedef unsigned int u32;
typedef short bf16x8 __attribute__((ext_vector_type(8)));
typedef float floatx4 __attribute__((ext_vector_type(4)));
typedef u16 u16x4 __attribute__((ext_vector_type(4)));

__device__ __forceinline__ u16 f2bf(float f) {
    u32 u = __builtin_bit_cast(u32, f);
    u32 r = (u + 0x7fffu + ((u >> 16) & 1u)) >> 16;
    return (u16)r;
}
__device__ __forceinline__ float bf2f(u16 b) {
    u32 u = ((u32)b) << 16;
    return __builtin_bit_cast(float, u);
}

__device__ __forceinline__ void gload_lds16(const void* g, void* l) {
    __builtin_amdgcn_global_load_lds((const __attribute__((address_space(1))) u32*)g,
                                     (__attribute__((address_space(3))) u32*)l, 16, 0, 0);
}

// ---------------- fused prep: input cvt + 6 weight transposes + bias concat ----------------
// grid: [0,8192) cvt x|pos ; [8192,14336) weight transpose ; [14336,14356) bias
__global__ void k_prep(const float* __restrict__ x, const float* __restrict__ pos,
                       u16* __restrict__ xb, u16* __restrict__ pb,
                       const float* __restrict__ Wq, const float* __restrict__ Wk,
                       const float* __restrict__ Wv, const float* __restrict__ Wpq,
                       const float* __restrict__ Wpk, const float* __restrict__ Wo,
                       u16* __restrict__ wtqkv, u16* __restrict__ wtp, u16* __restrict__ wto,
                       const float* __restrict__ bq, const float* __restrict__ bk,
                       const float* __restrict__ bv, const float* __restrict__ bpq,
                       const float* __restrict__ bpk,
                       float* __restrict__ bqkv, float* __restrict__ bp) {
    __shared__ float tile[32][33];
    const int id = blockIdx.x;
    if (id < 8192) {
        int i = id * 256 + threadIdx.x;              // float4 units
        const float* src = x; u16* dst = xb;
        int j = i;
        if (i >= 1048576) { src = pos; dst = pb; j = i - 1048576; }
        const floatx4 v = ((const floatx4*)src)[j];
        u16x4 o;
        o[0] = f2bf(v[0]); o[1] = f2bf(v[1]); o[2] = f2bf(v[2]); o[3] = f2bf(v[3]);
        ((u16x4*)dst)[j] = o;
    } else if (id < 14336) {
        const int wid = id - 8192;
        const int z = wid >> 10, rem = wid & 1023;
        const int bx = rem & 31, by = rem >> 5;
        const float* W; u16* Wt;
        switch (z) {
            case 0: W = Wq;  Wt = wtqkv;           break;
            case 1: W = Wk;  Wt = wtqkv + 1048576; break;
            case 2: W = Wv;  Wt = wtqkv + 2097152; break;
            case 3: W = Wpq; Wt = wtp;             break;
            case 4: W = Wpk; Wt = wtp + 1048576;   break;
            default: W = Wo; Wt = wto;             break;
        }
        const int tx = threadIdx.x & 31, ty = threadIdx.x >> 5;
        const int nb = bx << 5, kb = by << 5;
#pragma unroll
        for (int i = 0; i < 4; ++i)
            tile[ty + 8 * i][tx] = W[(size_t)(kb + ty + 8 * i) * 1024 + nb + tx];
        __syncthreads();
#pragma unroll
        for (int i = 0; i < 4; ++i)
            Wt[(size_t)(nb + ty + 8 * i) * 1024 + kb + tx] = f2bf(tile[tx][ty + 8 * i]);
    } else {
        int i = (id - 14336) * 256 + threadIdx.x;    // 0..5119
        if (i < 5120) {
            float v; float* d;
            if (i < 1024)      { v = bq[i];         d = bqkv + i; }
            else if (i < 2048) { v = bk[i - 1024];  d = bqkv + i; }
            else if (i < 3072) { v = bv[i - 2048];  d = bqkv + i; }
            else if (i < 4096) { v = bpq[i - 3072]; d = bp + (i - 3072); }
            else               { v = bpk[i - 4096]; d = bp + (i - 3072); }
            *d = v;
        }
    }
}

// ---------------- fused projection GEMM: [qkv | pqk] in one launch ----------------
// m97 structure: 128x128 tile, BK=64, 4 waves, global_load_lds w/ pre-swizzled source.
__launch_bounds__(256, 2)
__global__ void gemm_proj(const u16* __restrict__ A0, const u16* __restrict__ Bt0,
                          u16* __restrict__ C0, const float* __restrict__ bias0, int nblk0, int N0,
                          const u16* __restrict__ A1, const u16* __restrict__ Bt1,
                          u16* __restrict__ C1, const float* __restrict__ bias1, int N1,
                          int M, int K) {
    __shared__ u16 smA[128 * 64];
    __shared__ u16 smB[128 * 64];
    const int t = threadIdx.x;
    const int l = t & 63, w = t >> 6;
    const int bx = blockIdx.x;
    const u16* A; const u16* Bt; u16* C; const float* bias; int N, n0;
    if (bx < nblk0) { A = A0; Bt = Bt0; C = C0; bias = bias0; N = N0; n0 = bx << 7; }
    else            { A = A1; Bt = Bt1; C = C1; bias = bias1; N = N1; n0 = (bx - nblk0) << 7; }
    const int m0 = blockIdx.y << 7;
    const int wm = w & 1, wn = w >> 1;
    floatx4 acc[4][4];
#pragma unroll
    for (int a = 0; a < 4; ++a)
#pragma unroll
        for (int bq = 0; bq < 4; ++bq) { floatx4 z = {0.f, 0.f, 0.f, 0.f}; acc[a][bq] = z; }

    const int nkt = K >> 6;
    for (int kt = 0; kt < nkt; ++kt) {
        const int k0 = kt << 6;
#pragma unroll
        for (int i = 0; i < 4; ++i) {
            int o = (w << 12) + (i << 10) + (l << 4);
            int row = o >> 7, colb = o & 127;
            int sc = colb ^ ((row & 7) << 4);
            gload_lds16((const char*)A + ((size_t)(m0 + row) * K + k0) * 2 + sc,
                        (char*)smA + (w << 12) + (i << 10));
            gload_lds16((const char*)Bt + ((size_t)(n0 + row) * K + k0) * 2 + sc,
                        (char*)smB + (w << 12) + (i << 10));
        }
        __syncthreads();
#pragma unroll
        for (int ks = 0; ks < 2; ++ks) {
            const int kb = ((ks << 5) + ((l >> 4) << 3)) << 1;
            bf16x8 am[4], bn[4];
#pragma unroll
            for (int mt = 0; mt < 4; ++mt) {
                int row = (wm << 6) + (mt << 4) + (l & 15);
                am[mt] = *(const bf16x8*)((const char*)smA + row * 128 + (kb ^ ((row & 7) << 4)));
            }
#pragma unroll
            for (int nt = 0; nt < 4; ++nt) {
                int row = (wn << 6) + (nt << 4) + (l & 15);
                bn[nt] = *(const bf16x8*)((const char*)smB + row * 128 + (kb ^ ((row & 7) << 4)));
            }
#pragma unroll
            for (int mt = 0; mt < 4; ++mt)
#pragma unroll
                for (int nt = 0; nt < 4; ++nt)
                    acc[mt][nt] = __builtin_amdgcn_mfma_f32_16x16x32_bf16(am[mt], bn[nt], acc[mt][nt], 0, 0, 0);
        }
        __syncthreads();
    }
#pragma unroll
    for (int nt = 0; nt < 4; ++nt) {
        const int n = n0 + (wn << 6) + (nt << 4) + (l & 15);
        const float bv = bias[n];
#pragma unroll
        for (int mt = 0; mt < 4; ++mt) {
#pragma unroll
            for (int r = 0; r < 4; ++r) {
                int m = m0 + (wm << 6) + (mt << 4) + ((l >> 4) << 2) + r;
                C[(size_t)m * N + n] = f2bf(acc[mt][nt][r] + bv);
            }
        }
    }
}

// ---------------- final GEMM: 128Mx64N tile (512 blocks -> 2/CU fill), f32 out ----------------
__launch_bounds__(256, 2)
__global__ void gemm_out(const u16* __restrict__ A, const u16* __restrict__ Bt,
                         float* __restrict__ Cout, const float* __restrict__ bias,
                         int M, int N, int K) {
    __shared__ u16 smA[128 * 64];
    __shared__ u16 smB[64 * 64];
    const int t = threadIdx.x;
    const int l = t & 63, w = t >> 6;
    const int n0 = blockIdx.x << 6, m0 = blockIdx.y << 7;
    const int wm = w & 1, wn = w >> 1;
    floatx4 acc[4][2];
#pragma unroll
    for (int a = 0; a < 4; ++a)
#pragma unroll
        for (int bq = 0; bq < 2; ++bq) { floatx4 z = {0.f, 0.f, 0.f, 0.f}; acc[a][bq] = z; }

    const int nkt = K >> 6;
    for (int kt = 0; kt < nkt; ++kt) {
        const int k0 = kt << 6;
#pragma unroll
        for (int i = 0; i < 4; ++i) {
            int o = (i << 12) + (t << 4);
            int row = o >> 7, colb = o & 127;
            int sc = colb ^ ((row & 7) << 4);
            gload_lds16((const char*)A + ((size_t)(m0 + row) * K + k0) * 2 + sc,
                        (char*)smA + o);
        }
#pragma unroll
        for (int i = 0; i < 2; ++i) {
            int o = (i << 12) + (t << 4);
            int row = o >> 7, colb = o & 127;
            int sc = colb ^ ((row & 7) << 4);
            gload_lds16((const char*)Bt + ((size_t)(n0 + row) * K + k0) * 2 + sc,
                        (char*)smB + o);
        }
        __syncthreads();
#pragma unroll
        for (int ks = 0; ks < 2; ++ks) {
            const int kb = ((ks << 5) + ((l >> 4) << 3)) << 1;
            bf16x8 am[4], bn[2];
#pragma unroll
            for (int mt = 0; mt < 4; ++mt) {
                int row = (wm << 6) + (mt << 4) + (l & 15);
                am[mt] = *(const bf16x8*)((const char*)smA + row * 128 + (kb ^ ((row & 7) << 4)));
            }
#pragma unroll
            for (int nt = 0; nt < 2; ++nt) {
                int row = (wn << 5) + (nt << 4) + (l & 15);
                bn[nt] = *(const bf16x8*)((const char*)smB + row * 128 + (kb ^ ((row & 7) << 4)));
            }
#pragma unroll
            for (int mt = 0; mt < 4; ++mt)
#pragma unroll
                for (int nt = 0; nt < 2; ++nt)
                    acc[mt][nt] = __builtin_amdgcn_mfma_f32_16x16x32_bf16(am[mt], bn[nt], acc[mt][nt], 0, 0, 0);
        }
        __syncthreads();
    }
#pragma unroll
    for (int nt = 0; nt < 2; ++nt) {
        const int n = n0 + (wn << 5) + (nt << 4) + (l & 15);
        const float bv = bias[n];
#pragma unroll
        for (int mt = 0; mt < 4; ++mt) {
#pragma unroll
            for (int r = 0; r < 4; ++r) {
                int m = m0 + (wm << 6) + (mt << 4) + ((l >> 4) << 2) + r;
                Cout[(size_t)m * N + n] = acc[mt][nt][r] + bv;
            }
        }
    }
}

// ---------------- fused banded attention ----------------
// grid (16 qtiles, 16 heads, 4 batch), 256 threads (4 waves), 64 queries/block.
// 3 blocks/CU: LDS 50KB*3=150KB fits; phase-A live VGPRs ~150 fits 168-cap.
__launch_bounds__(256, 3)
__global__ void k_attn(const u16* __restrict__ qkv, const u16* __restrict__ pqk,
                       float* __restrict__ wei, u16* __restrict__ att) {
    __shared__ __align__(16) char sm[50176];
    u16* smQ  = (u16*)(sm);            // [64][64] swizzled (phase A)
    u16* smPQ = (u16*)(sm + 8192);
    u16* smK  = (u16*)(sm + 16384);
    u16* smKm = (u16*)(sm + 24576);
    u16* smP  = (u16*)(sm);            // [64 q][328 key] bf16 (phase B/C)
    u16* smVt = (u16*)(sm + 41984);    // [64 d][64 key] swizzled (phase C)

    const int t = threadIdx.x, l = t & 63, w = t >> 6;
    const int qt = blockIdx.x, h = blockIdx.y, b = blockIdx.z;
    const int q0 = qt << 6;
    const int jlo = (q0 - WIN) > 0 ? (q0 - WIN) : 0;
    const int nch = (qt + 1) < 5 ? (qt + 1) : 5;
    const int col_l = l & 15;
    const int rq_hi = (l >> 4) << 2;

    // ---- stage Q, PQ (pre-swizzled source -> linear LDS dest) ----
#pragma unroll
    for (int i = 0; i < 2; ++i) {
        int o = (w << 11) + (i << 10) + (l << 4);
        int row = o >> 7, colb = o & 127;
        int sc = colb ^ ((row & 7) << 4);
        gload_lds16((const char*)qkv + ((size_t)(b * 1024 + q0 + row) * 3072 + h * 64) * 2 + sc,
                    (char*)smQ + (w << 11) + (i << 10));
        gload_lds16((const char*)pqk + ((size_t)(b * 1024 + q0 + row) * 2048 + h * 64) * 2 + sc,
                    (char*)smPQ + (w << 11) + (i << 10));
    }

    // ---- early zero-fill of wei outside the band (overlaps load latency) ----
    {
        const int zlen1 = jlo;                 // [0, jlo)
        const int zstart2 = q0 + 64;           // [q0+64, 1024)
        const int nz4 = (zlen1 + (1024 - zstart2)) >> 2;
        float* wbase = wei + (((size_t)(b * NHEAD + h)) << 20);
        floatx4 z4 = {0.f, 0.f, 0.f, 0.f};
        for (int rr = w; rr < 64; rr += 4) {
            float* rowp = wbase + (((size_t)(q0 + rr)) << 10);
            for (int cc = l; cc < nz4; cc += 64) {
                int off4 = cc << 2;
                int col = (off4 < zlen1) ? off4 : (zstart2 + (off4 - zlen1));
                *(floatx4*)(rowp + col) = z4;
            }
        }
    }

    floatx4 acc[20];
#pragma unroll
    for (int i = 0; i < 20; ++i) { floatx4 z = {0.f, 0.f, 0.f, 0.f}; acc[i] = z; }

    // ---- phase A: score MFMAs with K/PK register prefetch ----
    const int prow = t >> 2, pd0 = (t & 3) << 4;
    bf16x8 rk0, rk1, rp0, rp1;
    {
        const u16* kp = qkv + (size_t)(b * 1024 + jlo + prow) * 3072 + 1024 + h * 64 + pd0;
        const u16* pp = pqk + (size_t)(b * 1024 + jlo + prow) * 2048 + 1024 + h * 64 + pd0;
        rk0 = *(const bf16x8*)kp; rk1 = *(const bf16x8*)(kp + 8);
        rp0 = *(const bf16x8*)pp; rp1 = *(const bf16x8*)(pp + 8);
    }
#pragma unroll
    for (int c = 0; c < 5; ++c) {
        if (c < nch) {
            const int jb = jlo + (c << 6);
            { // Kmod = k/8 + pk from prefetched regs -> swizzled LDS
                bf16x8 o0, o1;
#pragma unroll
                for (int j = 0; j < 8; ++j) {
                    o0[j] = (short)f2bf(0.125f * bf2f((u16)rk0[j]) + bf2f((u16)rp0[j]));
                    o1[j] = (short)f2bf(0.125f * bf2f((u16)rk1[j]) + bf2f((u16)rp1[j]));
                }
                const int sw = (prow & 7) << 4;
                *(bf16x8*)((char*)smKm + prow * 128 + ((pd0 * 2) ^ sw)) = o0;
                *(bf16x8*)((char*)smKm + prow * 128 + ((pd0 * 2 + 16) ^ sw)) = o1;
            }
#pragma unroll
            for (int i = 0; i < 2; ++i) {
                int o = (w << 11) + (i << 10) + (l << 4);
                int row = o >> 7, colb = o & 127;
                int sc = colb ^ ((row & 7) << 4);
                gload_lds16((const char*)qkv + ((size_t)(b * 1024 + jb + row) * 3072 + 1024 + h * 64) * 2 + sc,
                            (char*)smK + (w << 11) + (i << 10));
            }
            __syncthreads();
            if (c + 1 < nch) { // prefetch next chunk's K/PK into regs (overlaps MFMA)
                const int jb2 = jlo + ((c + 1) << 6);
                const u16* kp = qkv + (size_t)(b * 1024 + jb2 + prow) * 3072 + 1024 + h * 64 + pd0;
                const u16* pp = pqk + (size_t)(b * 1024 + jb2 + prow) * 2048 + 1024 + h * 64 + pd0;
                rk0 = *(const bf16x8*)kp; rk1 = *(const bf16x8*)(kp + 8);
                rp0 = *(const bf16x8*)pp; rp1 = *(const bf16x8*)(pp + 8);
            }
            __builtin_amdgcn_s_setprio(1);
#pragma unroll
            for (int ks = 0; ks < 2; ++ks) {
                const int kb = ((ks << 5) + ((l >> 4) << 3)) << 1;
                const int rq = (w << 4) + (l & 15);
                bf16x8 aQ  = *(const bf16x8*)((const char*)smQ  + rq * 128 + (kb ^ ((rq & 7) << 4)));
                bf16x8 aPQ = *(const bf16x8*)((const char*)smPQ + rq * 128 + (kb ^ ((rq & 7) << 4)));
#pragma unroll
                for (int s = 0; s < 4; ++s) {
                    const int rk = (s << 4) + (l & 15);
                    bf16x8 bKm = *(const bf16x8*)((const char*)smKm + rk * 128 + (kb ^ ((rk & 7) << 4)));
                    bf16x8 bK  = *(const bf16x8*)((const char*)smK  + rk * 128 + (kb ^ ((rk & 7) << 4)));
                    acc[c * 4 + s] = __builtin_amdgcn_mfma_f32_16x16x32_bf16(aQ,  bKm, acc[c * 4 + s], 0, 0, 0);
                    acc[c * 4 + s] = __builtin_amdgcn_mfma_f32_16x16x32_bf16(aPQ, bK,  acc[c * 4 + s], 0, 0, 0);
                }
            }
            __builtin_amdgcn_s_setprio(0);
            __syncthreads();
        }
    }

    // ---- phase B: softmax in MFMA-accumulator layout; write wei band + P(bf16) ----
    const float inv_s192 = 0.07216878364870323f; // 1/sqrt(3*64)
    const float slope = exp2f(-0.5f * (float)(h + 1));
    const int ntiles = nch << 2;
#pragma unroll
    for (int r = 0; r < 4; ++r) {
        const int iq = q0 + (w << 4) + rq_hi + r;
        float mx = -1e30f;
#pragma unroll
        for (int ti = 0; ti < 20; ++ti) {
            int j = jlo + (ti << 4) + col_l;
            float s = acc[ti][r] * inv_s192 - slope * (float)(iq - j);
            bool ok = (ti < ntiles) && (j <= iq) && (j >= iq - WIN);
            s = ok ? s : -1e30f;
            acc[ti][r] = s;
            mx = fmaxf(mx, s);
        }
        mx = fmaxf(mx, __shfl_xor(mx, 1));
        mx = fmaxf(mx, __shfl_xor(mx, 2));
        mx = fmaxf(mx, __shfl_xor(mx, 4));
        mx = fmaxf(mx, __shfl_xor(mx, 8));
        float sum = 0.f;
#pragma unroll
        for (int ti = 0; ti < 20; ++ti) {
            float p = __expf(acc[ti][r] - mx);
            acc[ti][r] = p;
            sum += p;
        }
        sum += __shfl_xor(sum, 1); sum += __shfl_xor(sum, 2);
        sum += __shfl_xor(sum, 4); sum += __shfl_xor(sum, 8);
        const float inv = 1.0f / sum;
        float* wrow = wei + ((((size_t)(b * NHEAD + h)) << 10) + iq) * 1024;
#pragma unroll
        for (int ti = 0; ti < 20; ++ti) {
            if (ti < ntiles) {
                float p = acc[ti][r] * inv;
                int j = jlo + (ti << 4) + col_l;
                wrow[j] = p;
                smP[((w << 4) + rq_hi + r) * 328 + (ti << 4) + col_l] = f2bf(p);
            }
        }
    }

    // ---- phase C: O = P * V  (V staged transposed, reg-prefetched) ----
    floatx4 acco[4];
#pragma unroll
    for (int s = 0; s < 4; ++s) { floatx4 z = {0.f, 0.f, 0.f, 0.f}; acco[s] = z; }
    const int vkey = t & 63, vdb = (t >> 6) << 4;
    bf16x8 v0, v1;
    {
        const u16* vp = qkv + (size_t)(b * 1024 + jlo + vkey) * 3072 + 2048 + h * 64 + vdb;
        v0 = *(const bf16x8*)vp; v1 = *(const bf16x8*)(vp + 8);
    }
#pragma unroll
    for (int c = 0; c < 5; ++c) {
        if (c < nch) {
            { // scatter prefetched V chunk -> smVt[d][key] (swizzled)
                const int kx = vkey << 1;
#pragma unroll
                for (int j = 0; j < 8; ++j) {
                    const int d0 = vdb + j, d1 = vdb + 8 + j;
                    *(u16*)((char*)smVt + d0 * 128 + (kx ^ ((d0 & 7) << 4))) = (u16)v0[j];
                    *(u16*)((char*)smVt + d1 * 128 + (kx ^ ((d1 & 7) << 4))) = (u16)v1[j];
                }
            }
            __syncthreads();
            if (c + 1 < nch) {
                const u16* vp = qkv + (size_t)(b * 1024 + jlo + ((c + 1) << 6) + vkey) * 3072 + 2048 + h * 64 + vdb;
                v0 = *(const bf16x8*)vp; v1 = *(const bf16x8*)(vp + 8);
            }
            __builtin_amdgcn_s_setprio(1);
#pragma unroll
            for (int ks = 0; ks < 2; ++ks) {
                const int rp = (w << 4) + (l & 15);
                const int keyb = ((c << 6) + (ks << 5) + ((l >> 4) << 3)) << 1;
                bf16x8 aP = *(const bf16x8*)((const char*)smP + rp * 656 + keyb);
                const int klb = ((ks << 5) + ((l >> 4) << 3)) << 1;
#pragma unroll
                for (int s = 0; s < 4; ++s) {
                    const int d = (s << 4) + col_l;
                    bf16x8 bV = *(const bf16x8*)((const char*)smVt + d * 128 + (klb ^ ((d & 7) << 4)));
                    acco[s] = __builtin_amdgcn_mfma_f32_16x16x32_bf16(aP, bV, acco[s], 0, 0, 0);
                }
            }
            __builtin_amdgcn_s_setprio(0);
            __syncthreads();
        }
    }
#pragma unroll
    for (int s = 0; s < 4; ++s) {
#pragma unroll
        for (int r = 0; r < 4; ++r) {
            const int iq = q0 + (w << 4) + rq_hi + r;
            const int d = (s << 4) + col_l;
            att[(((size_t)(b * 1024 + iq)) << 10) + h * 64 + d] = f2bf(acco[s][r]);
        }
    }
}

extern "C" void kernel_launch(void* const* d_in, const int* in_sizes, int n_in,
                              void* d_out, int out_size, void* d_ws, size_t ws_size,
                              hipStream_t stream) {
    const float* x   = (const float*)d_in[0];
    const float* pos = (const float*)d_in[1];
    const float* Wq  = (const float*)d_in[2];
    const float* bq  = (const float*)d_in[3];
    const float* Wk  = (const float*)d_in[4];
    const float* bk  = (const float*)d_in[5];
    const float* Wv  = (const float*)d_in[6];
    const float* bv  = (const float*)d_in[7];
    const float* Wpq = (const float*)d_in[8];
    const float* bpq = (const float*)d_in[9];
    const float* Wpk = (const float*)d_in[10];
    const float* bpk = (const float*)d_in[11];
    const float* Wo  = (const float*)d_in[12];
    const float* bo  = (const float*)d_in[13];

    char* ws = (char*)d_ws;
    u16*   xb    = (u16*)(ws);                 // 8 MB  [4096][1024] bf16 (reused as att)
    u16*   pb    = (u16*)(ws + 8388608);       // 8 MB
    u16*   wtqkv = (u16*)(ws + 16777216);      // 6 MB  [3072][1024]
    u16*   wtp   = (u16*)(ws + 23068672);      // 4 MB  [2048][1024]
    u16*   wto   = (u16*)(ws + 27262976);      // 2 MB  [1024][1024]
    float* bqkv  = (float*)(ws + 29360128);    // 12 KB
    float* bp    = (float*)(ws + 29372416);    // 8 KB
    u16*   qkv   = (u16*)(ws + 29380608);      // 24 MB [4096][3072]
    u16*   pqk   = (u16*)(ws + 54546432);      // 16 MB [4096][2048]
    u16*   att   = xb;                         // alias: xb dead after projection

    float* out0 = (float*)d_out;
    float* wei  = (float*)d_out + 4194304;

    k_prep<<<14356, 256, 0, stream>>>(x, pos, xb, pb,
                                      Wq, Wk, Wv, Wpq, Wpk, Wo, wtqkv, wtp, wto,
                                      bq, bk, bv, bpq, bpk, bqkv, bp);

    gemm_proj<<<dim3(40, 32), 256, 0, stream>>>(xb, wtqkv, qkv, bqkv, 24, 3072,
                                                pb, wtp, pqk, bp, 2048, 4096, 1024);

    k_attn<<<dim3(16, 16, 4), 256, 0, stream>>>(qkv, pqk, wei, att);

    gemm_out<<<dim3(16, 32), 256, 0, stream>>>(att, wto, out0, bo, 4096, 1024, 1024);
}